// Round 1
// baseline (84.408 us; speedup 1.0000x reference)
//
#include <hip/hip_runtime.h>

#define NPART 500000
#define MPART 450000
#define NBXC 1024
#define NBYC 1024
#define KWIN 8

// ---------------------------------------------------------------------------
// Kernel A: velocity field from potential (central differences, one-sided at
// boundaries) stored interleaved as float2 {vx,vy}; plus per-block partial
// sums of rho*(vx^2+vy^2) for the energy.
// ---------------------------------------------------------------------------
__global__ __launch_bounds__(256) void field_kernel(const float* __restrict__ pot,
                                                    const float* __restrict__ rho,
                                                    float2* __restrict__ v,
                                                    float* __restrict__ partials) {
    const int idx = blockIdx.x * 256 + threadIdx.x;   // 0 .. 1024*1024-1
    const int i = idx >> 10;    // x index (axis 0)
    const int j = idx & 1023;   // y index (axis 1)

    // d/dx (axis 0)
    float a, b, scale;
    if (i == 0)            { a = pot[1 * NBYC + j];        b = pot[0 * NBYC + j];        scale = 1.0f; }
    else if (i == NBXC - 1){ a = pot[(NBXC-1) * NBYC + j]; b = pot[(NBXC-2) * NBYC + j]; scale = 1.0f; }
    else                   { a = pot[(i+1) * NBYC + j];    b = pot[(i-1) * NBYC + j];    scale = 0.5f; }
    const float vx = -(a - b) * scale;

    // d/dy (axis 1)
    if (j == 0)            { a = pot[i * NBYC + 1];        b = pot[i * NBYC + 0];        scale = 1.0f; }
    else if (j == NBYC - 1){ a = pot[i * NBYC + NBYC-1];   b = pot[i * NBYC + NBYC-2];   scale = 1.0f; }
    else                   { a = pot[i * NBYC + j + 1];    b = pot[i * NBYC + j - 1];    scale = 0.5f; }
    const float vy = -(a - b) * scale;

    v[idx] = make_float2(vx, vy);

    float e = rho[idx] * (vx * vx + vy * vy);
    // wave64 reduce
    #pragma unroll
    for (int off = 32; off > 0; off >>= 1) e += __shfl_down(e, off, 64);
    __shared__ float smem[4];
    const int lane = threadIdx.x & 63;
    const int wid  = threadIdx.x >> 6;
    if (lane == 0) smem[wid] = e;
    __syncthreads();
    if (threadIdx.x == 0) partials[blockIdx.x] = (smem[0] + smem[1]) + (smem[2] + smem[3]);
}

// ---------------------------------------------------------------------------
// Kernel B: deterministic reduction of 4096 partials -> energy scalar.
// ---------------------------------------------------------------------------
__global__ __launch_bounds__(1024) void reduce_kernel(const float* __restrict__ partials,
                                                      float* __restrict__ out) {
    const int t = threadIdx.x;
    float e = (partials[t] + partials[t + 1024]) + (partials[t + 2048] + partials[t + 3072]);
    #pragma unroll
    for (int off = 32; off > 0; off >>= 1) e += __shfl_down(e, off, 64);
    __shared__ float smem[16];
    const int lane = t & 63;
    const int wid  = t >> 6;
    if (lane == 0) smem[wid] = e;
    __syncthreads();
    if (t == 0) {
        float s = 0.0f;
        #pragma unroll
        for (int k = 0; k < 16; ++k) s += smem[k];
        out[0] = 0.5f * s;
    }
}

// ---------------------------------------------------------------------------
// Kernel C: per-particle flux interpolation (bilinear for small nodes,
// area-overlap-window average for large nodes).
// ---------------------------------------------------------------------------
__global__ __launch_bounds__(256) void particle_kernel(const float* __restrict__ pos,
                                                       const float* __restrict__ nsx,
                                                       const float* __restrict__ nsy,
                                                       const float2* __restrict__ v,
                                                       float* __restrict__ out) {
    const int i = blockIdx.x * 256 + threadIdx.x;
    if (i >= MPART) return;

    const float px = pos[i];
    const float py = pos[NPART + i];
    const float w  = nsx[i];
    const float h  = nsy[i];

    // ---- bilinear path ----
    const float gx = px;             // XL=0, BSX=1
    const float gy = py;
    int ix = (int)floorf(gx); ix = min(max(ix, 0), NBXC - 1);
    int iy = (int)floorf(gy); iy = min(max(iy, 0), NBYC - 1);
    const float wx = fminf(fmaxf(gx - (float)ix, 0.0f), 1.0f);
    const float wy = fminf(fmaxf(gy - (float)iy, 0.0f), 1.0f);
    const int ix1 = min(ix + 1, NBXC - 1);
    const int iy1 = min(iy + 1, NBYC - 1);
    const float2 f00 = v[ix  * NBYC + iy ];
    const float2 f10 = v[ix1 * NBYC + iy ];
    const float2 f01 = v[ix  * NBYC + iy1];
    const float2 f11 = v[ix1 * NBYC + iy1];
    const float w00 = (1.0f - wx) * (1.0f - wy);
    const float w10 = wx * (1.0f - wy);
    const float w01 = (1.0f - wx) * wy;
    const float w11 = wx * wy;
    const float bfx = w00 * f00.x + w10 * f10.x + w01 * f01.x + w11 * f11.x;
    const float bfy = w00 * f00.y + w10 * f10.y + w01 * f01.y + w11 * f11.y;

    // ---- area-window path ----
    const float lx = px - 0.5f * w, rx = px + 0.5f * w;
    const float ly = py - 0.5f * h, ry = py + 0.5f * h;
    const int bminx = min(max((int)floorf(lx), 0), NBXC - 1);
    const int bmaxx = min(max((int)floorf(rx), 0), NBXC - 1);
    const int bminy = min(max((int)floorf(ly), 0), NBYC - 1);
    const int bmaxy = min(max((int)floorf(ry), 0), NBYC - 1);

    float oy[KWIN];
    int   byi[KWIN];
    #pragma unroll
    for (int k = 0; k < KWIN; ++k) {
        const int b = bminy + k;
        const float bl = (float)b;
        float ov = fminf(ry, bl + 1.0f) - fmaxf(ly, bl);
        ov = (b <= bmaxy && ov > 0.0f) ? ov : 0.0f;
        oy[k]  = ov;
        byi[k] = min(b, NBYC - 1);
    }

    float afx = 0.0f, afy = 0.0f;
    #pragma unroll
    for (int kx = 0; kx < KWIN; ++kx) {
        const int b = bminx + kx;
        const float bl = (float)b;
        float ov = fminf(rx, bl + 1.0f) - fmaxf(lx, bl);
        ov = (b <= bmaxx && ov > 0.0f) ? ov : 0.0f;
        if (ov == 0.0f) continue;
        const int bx = min(b, NBXC - 1);
        const float2* row = v + bx * NBYC;
        float sx = 0.0f, sy = 0.0f;
        #pragma unroll
        for (int ky = 0; ky < KWIN; ++ky) {
            const float o = oy[ky];
            if (o == 0.0f) continue;
            const float2 f = row[byi[ky]];
            sx += f.x * o;
            sy += f.y * o;
        }
        afx += sx * ov;
        afy += sy * ov;
    }
    const float area = w * h;
    const float inv  = 1.0f / fmaxf(area, 1e-30f);
    afx *= inv;
    afy *= inv;

    const bool large = (w >= 1.0f) || (h >= 1.0f);
    out[1 + i]         = large ? afx : bfx;
    out[1 + NPART + i] = large ? afy : bfy;
}

extern "C" void kernel_launch(void* const* d_in, const int* in_sizes, int n_in,
                              void* d_out, int out_size, void* d_ws, size_t ws_size,
                              hipStream_t stream) {
    const float* pos = (const float*)d_in[0];
    const float* pot = (const float*)d_in[1];
    const float* rho = (const float*)d_in[2];
    const float* nsx = (const float*)d_in[3];
    const float* nsy = (const float*)d_in[4];
    float* out = (float*)d_out;

    float2* v        = (float2*)d_ws;                                    // 1024*1024 float2 = 8 MB
    float*  partials = (float*)((char*)d_ws + (size_t)NBXC * NBYC * sizeof(float2)); // 4096 floats

    // zero the untouched grad regions [M:N) and [N+M:2N)
    hipMemsetAsync(out + 1 + MPART,         0, (size_t)(NPART - MPART) * sizeof(float), stream);
    hipMemsetAsync(out + 1 + NPART + MPART, 0, (size_t)(NPART - MPART) * sizeof(float), stream);

    field_kernel<<<(NBXC * NBYC) / 256, 256, 0, stream>>>(pot, rho, v, partials);
    reduce_kernel<<<1, 1024, 0, stream>>>(partials, out);
    particle_kernel<<<(MPART + 255) / 256, 256, 0, stream>>>(pos, nsx, nsy, v, out);
}